// Round 4
// baseline (214.380 us; speedup 1.0000x reference)
//
#include <hip/hip_runtime.h>

#define NB 4
#define CC 64
#define HW 4096
#define NT (NB*HW)
#define EPSV 1e-5f
#define LOG2E 1.4426950408889634f
#define THRV 8.0f   // defer-max threshold (exp2 domain): p <= 2^8, f16-safe

typedef _Float16 f16;
typedef _Float16 half4 __attribute__((ext_vector_type(4)));
typedef _Float16 half8 __attribute__((ext_vector_type(8)));
typedef float   float4v __attribute__((ext_vector_type(4)));

#define NELEM ((size_t)NB*HW*CC)   // 1,048,576 per tensor
#define NSLOT 128                  // conv2 partial-stat slots (NB * HW/128)

// ws: fp32 [512..512+NSLOT*256): per-(n,bx) partial BN stats.
// Byte 264192+: f16 q, k ([n][hw][c]) and gv ([n][c][hw]) — 3 x 2 MB.
#define PART_OFF 512
#define TEN_OFF  264192

// ---------------------------------------------------------------------------
// conv2: 3 fused 1x1 convs; 128 px/block (2 adjacent px per thread), 4-way
// channel split over blockIdx.z. grid (HW/128, NB, 4), 256 thr. (r12, kept —
// measured: non-attn pipeline total ~36 µs)
// ---------------------------------------------------------------------------
__global__ __launch_bounds__(256)
void conv2_kernel(const float* __restrict__ x,
                  const float* __restrict__ h0, const float* __restrict__ h1,
                  const float* __restrict__ Wq, const float* __restrict__ bq,
                  const float* __restrict__ Wk, const float* __restrict__ bk,
                  const float* __restrict__ Wv, const float* __restrict__ bv,
                  float* __restrict__ ws,
                  f16* __restrict__ q, f16* __restrict__ k, f16* __restrict__ gv)
{
    __shared__ float Wl[3][16*CC];   // 12 KB
    __shared__ float xs[CC][128];    // 32 KB
    const int t    = threadIdx.x;
    const int n    = blockIdx.y;
    const int z    = blockIdx.z;
    const int px0  = blockIdx.x * 128;
    const int lane = t & 63;
    const int grp  = t >> 6;
    const int ocl  = grp * 4;
    const int oc0  = z*16 + ocl;

    ((float4*)Wl[0])[t] = ((const float4*)(Wq + (size_t)z*16*CC))[t];
    ((float4*)Wl[1])[t] = ((const float4*)(Wk + (size_t)z*16*CC))[t];
    ((float4*)Wl[2])[t] = ((const float4*)(Wv + (size_t)z*16*CC))[t];
    for (int i = t; i < CC*32; i += 256) {          // 2048 float4
        int ic = i >> 5, c4 = i & 31;
        ((float4*)&xs[ic][0])[c4] =
            ((const float4*)(x + ((size_t)n*CC + ic)*HW + px0))[c4];
    }
    __syncthreads();

    float aq[4][2], ak[4][2], av[4][2];
    #pragma unroll
    for (int j = 0; j < 4; ++j) {
        aq[j][0] = aq[j][1] = bq[oc0+j];
        ak[j][0] = ak[j][1] = bk[oc0+j];
        av[j][0] = av[j][1] = bv[oc0+j];
    }

    for (int ic = 0; ic < CC; ic += 4) {
        float2 xv0 = *(float2*)&xs[ic  ][lane*2];
        float2 xv1 = *(float2*)&xs[ic+1][lane*2];
        float2 xv2 = *(float2*)&xs[ic+2][lane*2];
        float2 xv3 = *(float2*)&xs[ic+3][lane*2];
        #pragma unroll
        for (int j = 0; j < 4; ++j) {
            const int row = (ocl+j)*CC + ic;
            float4 wq = *(const float4*)&Wl[0][row];
            float4 wk = *(const float4*)&Wl[1][row];
            float4 wv = *(const float4*)&Wl[2][row];
            aq[j][0] = fmaf(wq.x,xv0.x, fmaf(wq.y,xv1.x, fmaf(wq.z,xv2.x, fmaf(wq.w,xv3.x, aq[j][0]))));
            aq[j][1] = fmaf(wq.x,xv0.y, fmaf(wq.y,xv1.y, fmaf(wq.z,xv2.y, fmaf(wq.w,xv3.y, aq[j][1]))));
            ak[j][0] = fmaf(wk.x,xv0.x, fmaf(wk.y,xv1.x, fmaf(wk.z,xv2.x, fmaf(wk.w,xv3.x, ak[j][0]))));
            ak[j][1] = fmaf(wk.x,xv0.y, fmaf(wk.y,xv1.y, fmaf(wk.z,xv2.y, fmaf(wk.w,xv3.y, ak[j][1]))));
            av[j][0] = fmaf(wv.x,xv0.x, fmaf(wv.y,xv1.x, fmaf(wv.z,xv2.x, fmaf(wv.w,xv3.x, av[j][0]))));
            av[j][1] = fmaf(wv.x,xv0.y, fmaf(wv.y,xv1.y, fmaf(wv.z,xv2.y, fmaf(wv.w,xv3.y, av[j][1]))));
        }
    }

    const int px = px0 + lane*2;
    const size_t base = ((size_t)n*HW + px)*CC + oc0;
    half4 vq0, vq1, vk0, vk1;
    #pragma unroll
    for (int j = 0; j < 4; ++j) {
        vq0[j] = (f16)aq[j][0]; vq1[j] = (f16)aq[j][1];
        vk0[j] = (f16)ak[j][0]; vk1[j] = (f16)ak[j][1];
    }
    *(half4*)&q[base]      = vq0;  *(half4*)&q[base + CC] = vq1;
    *(half4*)&k[base]      = vk0;  *(half4*)&k[base + CC] = vk1;

    #pragma unroll
    for (int j = 0; j < 4; ++j) {
        size_t gi = ((size_t)n*CC + oc0 + j)*HW + px;
        f16 g0 = (f16)((h0[gi]   + h1[gi]  ) * av[j][0]);
        f16 g1 = (f16)((h0[gi+1] + h1[gi+1]) * av[j][1]);
        gv[gi]   = g0;
        gv[gi+1] = g1;
    }

    float* slot = ws + PART_OFF + (size_t)(n*(HW/128) + blockIdx.x)*256;
    #pragma unroll
    for (int j = 0; j < 4; ++j) {
        float v0 = aq[j][0] + aq[j][1];
        float v1 = aq[j][0]*aq[j][0] + aq[j][1]*aq[j][1];
        float v2 = ak[j][0] + ak[j][1];
        float v3 = ak[j][0]*ak[j][0] + ak[j][1]*ak[j][1];
        #pragma unroll
        for (int off = 32; off > 0; off >>= 1) {
            v0 += __shfl_down(v0, off);
            v1 += __shfl_down(v1, off);
            v2 += __shfl_down(v2, off);
            v3 += __shfl_down(v3, off);
        }
        if (lane == 0) {
            slot[      oc0 + j] = v0;
            slot[ 64 + oc0 + j] = v1;
            slot[128 + oc0 + j] = v2;
            slot[192 + oc0 + j] = v3;
        }
    }
}

// ---------------------------------------------------------------------------
// apply: folds BN stats redundantly per block, then y = relu(s*y+t) in place,
// 16 f16/thread. blockIdx.y: 0=q, 1=k (k pre-scaled by log2e). (r12, kept)
// ---------------------------------------------------------------------------
__global__ __launch_bounds__(256)
void apply_kernel(f16* __restrict__ q, f16* __restrict__ k,
                  const float* __restrict__ ws,
                  const float* __restrict__ gq, const float* __restrict__ betaq,
                  const float* __restrict__ gk, const float* __restrict__ betak)
{
    __shared__ float tot[128];
    __shared__ float sc[CC], sh[CC];
    const int t = threadIdx.x;
    const int tens = blockIdx.y;

    if (t < 128) {
        const float* base = ws + PART_OFF + tens*128 + t;
        float acc = 0.0f;
        #pragma unroll 8
        for (int s = 0; s < NSLOT; ++s) acc += base[(size_t)s*256];
        tot[t] = acc;
    }
    __syncthreads();
    if (t < 64) {
        float mean = tot[t] * (1.0f / NT);
        float var  = tot[64 + t] * (1.0f / NT) - mean*mean;
        if (tens == 0) {
            float s = gq[t] * rsqrtf(var + EPSV);
            sc[t] = s;  sh[t] = betaq[t] - mean*s;
        } else {
            float s = gk[t] * rsqrtf(var + EPSV);
            sc[t] = s * LOG2E;  sh[t] = (betak[t] - mean*s) * LOG2E;
        }
    }
    __syncthreads();

    f16* p = tens ? k : q;
    const size_t e0 = ((size_t)blockIdx.x * 256 + t) * 16;
    const int c0 = (int)(e0 & 63);

    half8 v0 = *(half8*)&p[e0], v1 = *(half8*)&p[e0 + 8];
    half8 o0, o1;
    #pragma unroll
    for (int j = 0; j < 8; ++j) {
        o0[j] = (f16)fmaxf(fmaf(sc[c0+j],   (float)v0[j], sh[c0+j]),   0.0f);
        o1[j] = (f16)fmaxf(fmaf(sc[c0+8+j], (float)v1[j], sh[c0+8+j]), 0.0f);
    }
    *(half8*)&p[e0]     = o0;
    *(half8*)&p[e0 + 8] = o1;
}

// ---------------------------------------------------------------------------
// MFMA flash attention — r17: true K double-buffer UNDER the 128-reg cap.
// Constraint algebra from r13-r16:
//   r13: dbuf + 4qt ILP, ~196 total regs -> 2 waves/SIMD, 66 µs.
//   r14: dbuf + 2qt at (512,4) 128-cap -> spill (WRITE_SIZE 110 MB), 144 µs.
//   r15: no dbuf + 2qt, fits (104 regs), Occ 38% -> 98 µs (latency exposed).
//   r16: rotating same-reg prefetch -> neutral 100 µs (WAR defeats pipeline).
// Occupancy without pipelining loses to pipelining without occupancy; r17
// runs BOTH: khf gets a TRUE 2-buffer (separate regs, prefetch next tile at
// step top, full-step slack), paid for by (a) accL via per-lane scalar VALU
// sum instead of ones-MFMA (-8 AGPR, -4 MFMA/step; cross-quad shfl deferred
// to publish), (b) defer-max THR=8 (T13): skip the 34-op rescale unless
// mx > m+8; p <= 2^8 is f16-safe, merge frame valid for stale m.
// Budget: qf16 + khf32 + gvf16 + accO32 + accS16 + misc ~12 = ~122 <= 128.
// SUCCESS CRITERIA: WRITE_SIZE ~4 MB (no spill), MfmaUtil > 20%, attn < 60 µs.
// r12's 16x16x32 PV restructure spilled ~190 MB — do NOT reintroduce.
// Layout (validated r4-r11): mfma(X,Y) -> D[p=quad*4+reg <- X row][q=lane&15 <- Y row].
// ---------------------------------------------------------------------------
__global__ __launch_bounds__(512, 4)
void attn_kernel(const f16* __restrict__ q, const f16* __restrict__ k,
                 const f16* __restrict__ gv, float* __restrict__ out)
{
    __shared__ float Obuf[8][4][256];   // [wave][ct][lane*4] — 32 KB, reused 2x
    __shared__ float MLbuf[2][8][32];   // [m|l][wave][qrow]  — 2 KB

    const int t    = threadIdx.x;
    const int n    = blockIdx.y;
    const int w    = t >> 6;
    const int lane = t & 63;
    const int m16  = lane & 15;
    const int kb   = lane >> 4;
    const int q0   = blockIdx.x * 32;

    half8 qf[2][2];
    #pragma unroll
    for (int qt = 0; qt < 2; ++qt) {
        const size_t qb = ((size_t)n*HW + q0 + qt*16 + m16)*CC + kb*8;
        qf[qt][0] = *(const half8*)&q[qb];
        qf[qt][1] = *(const half8*)&q[qb + 32];
    }

    const int    kt0   = w * 512;
    const size_t krow  = (size_t)n*HW*CC;
    const size_t gbase = ((size_t)n*CC + m16)*HW;

    half8 khf[2][2][2];     // [buf][ktile][chalf] — TRUE double buffer
    half4 gvf[2][4];        // [ktile][ct] — single buffer, r16-style rotate

#define LOADK(DST, KT) do {                                                   \
    size_t a_ = krow + ((size_t)(KT) + m16)*CC + kb*8;                        \
    khf[DST][0][0] = *(const half8*)&k[a_];                                   \
    khf[DST][0][1] = *(const half8*)&k[a_ + 32];                              \
    khf[DST][1][0] = *(const half8*)&k[a_ + 16*CC];                           \
    khf[DST][1][1] = *(const half8*)&k[a_ + 16*CC + 32];                      \
} while (0)

#define LOADGV(KT) do {                                                       \
    size_t g_ = gbase + (size_t)(KT) + kb*4;                                  \
    _Pragma("unroll") for (int k2_ = 0; k2_ < 2; ++k2_)                       \
    _Pragma("unroll") for (int ct_ = 0; ct_ < 4; ++ct_)                       \
        gvf[k2_][ct_] = *(const half4*)&gv[g_ + k2_*16 + (size_t)ct_*16*HW];  \
} while (0)

    float4v accO[2][4];
    #pragma unroll
    for (int qt = 0; qt < 2; ++qt)
        #pragma unroll
        for (int ct = 0; ct < 4; ++ct) accO[qt][ct] = (float4v){0.f,0.f,0.f,0.f};
    float accL[2] = {0.f, 0.f};          // per-lane partial l (own 8 keys/step)
    float m[2]    = {-INFINITY,-INFINITY};

// STEP: compute on khf[B] / gvf; prefetch tile KTN into khf[B^1] (true dbuf)
// and rotate gvf to KTN after PV consumes it (slack = next QK+softmax).
#define STEP(B, KTN) do {                                                     \
    LOADK((B)^1, KTN);  /* next tile K, separate buffer, full-step slack */   \
    float4v accS[2][2];                                                       \
    _Pragma("unroll") for (int qt_ = 0; qt_ < 2; ++qt_)                       \
    _Pragma("unroll") for (int k2_ = 0; k2_ < 2; ++k2_) {                     \
        float4v z_ = {0.f,0.f,0.f,0.f};                                       \
        z_ = __builtin_amdgcn_mfma_f32_16x16x32_f16(khf[B][k2_][0], qf[qt_][0], z_, 0,0,0); \
        accS[qt_][k2_] = __builtin_amdgcn_mfma_f32_16x16x32_f16(khf[B][k2_][1], qf[qt_][1], z_, 0,0,0); \
    }                                                                         \
    float mx[2];                                                              \
    _Pragma("unroll") for (int qt_ = 0; qt_ < 2; ++qt_) {                     \
        float va_ = fmaxf(fmaxf(accS[qt_][0][0], accS[qt_][0][1]), accS[qt_][0][2]); \
        float vb_ = fmaxf(fmaxf(accS[qt_][0][3], accS[qt_][1][0]), accS[qt_][1][1]); \
        float vc_ = fmaxf(fmaxf(accS[qt_][1][2], accS[qt_][1][3]), va_);      \
        float v_  = fmaxf(vb_, vc_);                                          \
        v_ = fmaxf(v_, __shfl_xor(v_, 16));                                   \
        v_ = fmaxf(v_, __shfl_xor(v_, 32));                                   \
        mx[qt_] = v_;                                                         \
    }                                                                         \
    int need_ = (mx[0] > m[0] + THRV) | (mx[1] > m[1] + THRV);                \
    if (__any(need_)) {                                                       \
        _Pragma("unroll") for (int qt_ = 0; qt_ < 2; ++qt_) {                 \
            float mn_ = fmaxf(m[qt_], mx[qt_]);                               \
            float al_ = exp2f(m[qt_] - mn_);                                  \
            m[qt_] = mn_;                                                     \
            accL[qt_] *= al_;                                                 \
            _Pragma("unroll") for (int ct_ = 0; ct_ < 4; ++ct_) {             \
                accO[qt_][ct_][0]*=al_; accO[qt_][ct_][1]*=al_;               \
                accO[qt_][ct_][2]*=al_; accO[qt_][ct_][3]*=al_;               \
            }                                                                 \
        }                                                                     \
    }                                                                         \
    _Pragma("unroll") for (int qt_ = 0; qt_ < 2; ++qt_) {                     \
        float p0 = exp2f(accS[qt_][0][0]-m[qt_]), p1 = exp2f(accS[qt_][0][1]-m[qt_]); \
        float p2 = exp2f(accS[qt_][0][2]-m[qt_]), p3 = exp2f(accS[qt_][0][3]-m[qt_]); \
        float p4 = exp2f(accS[qt_][1][0]-m[qt_]), p5 = exp2f(accS[qt_][1][1]-m[qt_]); \
        float p6 = exp2f(accS[qt_][1][2]-m[qt_]), p7 = exp2f(accS[qt_][1][3]-m[qt_]); \
        accL[qt_] += ((p0+p1)+(p2+p3)) + ((p4+p5)+(p6+p7));                   \
        half4 pfa, pfb;                                                       \
        pfa[0]=(f16)p0; pfa[1]=(f16)p1; pfa[2]=(f16)p2; pfa[3]=(f16)p3;       \
        pfb[0]=(f16)p4; pfb[1]=(f16)p5; pfb[2]=(f16)p6; pfb[3]=(f16)p7;       \
        _Pragma("unroll") for (int ct_ = 0; ct_ < 4; ++ct_) {                 \
            float4v o_ = accO[qt_][ct_];                                      \
            o_ = __builtin_amdgcn_mfma_f32_16x16x16f16(gvf[0][ct_], pfa, o_, 0,0,0); \
            accO[qt_][ct_] = __builtin_amdgcn_mfma_f32_16x16x16f16(gvf[1][ct_], pfb, o_, 0,0,0); \
        }                                                                     \
    }                                                                         \
    LOADGV(KTN);  /* gvf rotate — consumed next step's PV, wide slack */      \
} while (0)

    LOADK(0, kt0);
    LOADGV(kt0);
    #pragma unroll 2
    for (int i2 = 0; i2 < 16; ++i2) {
        STEP(i2 & 1, kt0 + (i2+1)*32);   // final prefetch overreads ws slack
    }

    // cross-quad l sum (deferred from the loop), then publish (m, l)
    float lsum[2];
    #pragma unroll
    for (int qt = 0; qt < 2; ++qt) {
        float l = accL[qt];
        l += __shfl_xor(l, 16);
        l += __shfl_xor(l, 32);
        lsum[qt] = l;
    }
    if (kb == 0) {
        #pragma unroll
        for (int qt = 0; qt < 2; ++qt) {
            MLbuf[0][w][qt*16 + m16] = m[qt];
            MLbuf[1][w][qt*16 + m16] = lsum[qt];
        }
    }
    __syncthreads();

    // global M, L per q-row; scale own partials into the shared frame
    float invL[2];
    #pragma unroll
    for (int qt = 0; qt < 2; ++qt) {
        const int r = qt*16 + m16;
        float M = MLbuf[0][0][r];
        #pragma unroll
        for (int src = 1; src < 8; ++src) M = fmaxf(M, MLbuf[0][src][r]);
        float L = 0.0f;
        #pragma unroll
        for (int src = 0; src < 8; ++src)
            L += MLbuf[1][src][r] * exp2f(MLbuf[0][src][r] - M);
        const float f = exp2f(m[qt] - M);
        #pragma unroll
        for (int ct = 0; ct < 4; ++ct) {
            accO[qt][ct][0] *= f; accO[qt][ct][1] *= f;
            accO[qt][ct][2] *= f; accO[qt][ct][3] *= f;
        }
        invL[qt] = 1.0f / L;
    }

    // 2 staged merge rounds: round rd handles q-tile rd
    for (int rd = 0; rd < 2; ++rd) {
        __syncthreads();
        #pragma unroll
        for (int ct = 0; ct < 4; ++ct)
            ((float4*)&Obuf[w][ct][0])[lane] =
                (float4){accO[rd][ct][0], accO[rd][ct][1], accO[rd][ct][2], accO[rd][ct][3]};
        __syncthreads();
        if (w < 4) {
            float4 s = ((float4*)&Obuf[0][w][0])[lane];
            #pragma unroll
            for (int src = 1; src < 8; ++src) {
                float4 v = ((float4*)&Obuf[src][w][0])[lane];
                s.x += v.x; s.y += v.y; s.z += v.z; s.w += v.w;
            }
            const float iv = invL[rd];
            const int chb = w*16 + kb*4;
            const int row = q0 + rd*16 + m16;
            out[((size_t)n*CC + chb + 0)*HW + row] = s.x * iv;
            out[((size_t)n*CC + chb + 1)*HW + row] = s.y * iv;
            out[((size_t)n*CC + chb + 2)*HW + row] = s.z * iv;
            out[((size_t)n*CC + chb + 3)*HW + row] = s.w * iv;
        }
    }
#undef STEP
#undef LOADGV
#undef LOADK
}

// ---------------------------------------------------------------------------
extern "C" void kernel_launch(void* const* d_in, const int* in_sizes, int n_in,
                              void* d_out, int out_size, void* d_ws, size_t ws_size,
                              hipStream_t stream)
{
    const float* low   = (const float*)d_in[0];
    const float* h0    = (const float*)d_in[1];
    const float* h1    = (const float*)d_in[2];
    const float* Wq    = (const float*)d_in[3];
    const float* bq    = (const float*)d_in[4];
    const float* gq    = (const float*)d_in[5];
    const float* betaq = (const float*)d_in[6];
    const float* Wk    = (const float*)d_in[7];
    const float* bk    = (const float*)d_in[8];
    const float* gk    = (const float*)d_in[9];
    const float* betak = (const float*)d_in[10];
    const float* Wv    = (const float*)d_in[11];
    const float* bv    = (const float*)d_in[12];

    float* wsf = (float*)d_ws;
    float* out = (float*)d_out;

    f16* q  = (f16*)((char*)d_ws + TEN_OFF);
    f16* k  = q + NELEM;
    f16* gv = k + NELEM;

    conv2_kernel<<<dim3(HW/128, NB, 4), 256, 0, stream>>>(
        low, h0, h1, Wq, bq, Wk, bk, Wv, bv, wsf, q, k, gv);

    apply_kernel<<<dim3((int)(NELEM/(256*16)), 2), 256, 0, stream>>>(
        q, k, wsf, gq, betaq, gk, betak);

    attn_kernel<<<dim3(HW/32, NB), 512, 0, stream>>>(q, k, gv, out);
}

// Round 5
// 160.246 us; speedup vs baseline: 1.3378x; 1.3378x over previous
//
#include <hip/hip_runtime.h>

#define NB 4
#define CC 64
#define HW 4096
#define NT (NB*HW)
#define EPSV 1e-5f
#define LOG2E 1.4426950408889634f
#define THRV 8.0f   // defer-max threshold (exp2 domain): p <= 2^8, f16-safe

typedef _Float16 f16;
typedef _Float16 half4 __attribute__((ext_vector_type(4)));
typedef _Float16 half8 __attribute__((ext_vector_type(8)));
typedef float   float4v __attribute__((ext_vector_type(4)));

#define NELEM ((size_t)NB*HW*CC)   // 1,048,576 per tensor
#define NSLOT 128                  // conv2 partial-stat slots (NB * HW/128)

// ws: fp32 [512..512+NSLOT*256): per-(n,bx) partial BN stats.
// Byte 264192+: f16 q, k ([n][hw][c]) and gv ([n][c][hw]) — 3 x 2 MB.
#define PART_OFF 512
#define TEN_OFF  264192

// ---------------------------------------------------------------------------
// conv2: 3 fused 1x1 convs; 128 px/block (2 adjacent px per thread), 4-way
// channel split over blockIdx.z. grid (HW/128, NB, 4), 256 thr. (r12, kept)
// ---------------------------------------------------------------------------
__global__ __launch_bounds__(256)
void conv2_kernel(const float* __restrict__ x,
                  const float* __restrict__ h0, const float* __restrict__ h1,
                  const float* __restrict__ Wq, const float* __restrict__ bq,
                  const float* __restrict__ Wk, const float* __restrict__ bk,
                  const float* __restrict__ Wv, const float* __restrict__ bv,
                  float* __restrict__ ws,
                  f16* __restrict__ q, f16* __restrict__ k, f16* __restrict__ gv)
{
    __shared__ float Wl[3][16*CC];   // 12 KB
    __shared__ float xs[CC][128];    // 32 KB
    const int t    = threadIdx.x;
    const int n    = blockIdx.y;
    const int z    = blockIdx.z;
    const int px0  = blockIdx.x * 128;
    const int lane = t & 63;
    const int grp  = t >> 6;
    const int ocl  = grp * 4;
    const int oc0  = z*16 + ocl;

    ((float4*)Wl[0])[t] = ((const float4*)(Wq + (size_t)z*16*CC))[t];
    ((float4*)Wl[1])[t] = ((const float4*)(Wk + (size_t)z*16*CC))[t];
    ((float4*)Wl[2])[t] = ((const float4*)(Wv + (size_t)z*16*CC))[t];
    for (int i = t; i < CC*32; i += 256) {          // 2048 float4
        int ic = i >> 5, c4 = i & 31;
        ((float4*)&xs[ic][0])[c4] =
            ((const float4*)(x + ((size_t)n*CC + ic)*HW + px0))[c4];
    }
    __syncthreads();

    float aq[4][2], ak[4][2], av[4][2];
    #pragma unroll
    for (int j = 0; j < 4; ++j) {
        aq[j][0] = aq[j][1] = bq[oc0+j];
        ak[j][0] = ak[j][1] = bk[oc0+j];
        av[j][0] = av[j][1] = bv[oc0+j];
    }

    for (int ic = 0; ic < CC; ic += 4) {
        float2 xv0 = *(float2*)&xs[ic  ][lane*2];
        float2 xv1 = *(float2*)&xs[ic+1][lane*2];
        float2 xv2 = *(float2*)&xs[ic+2][lane*2];
        float2 xv3 = *(float2*)&xs[ic+3][lane*2];
        #pragma unroll
        for (int j = 0; j < 4; ++j) {
            const int row = (ocl+j)*CC + ic;
            float4 wq = *(const float4*)&Wl[0][row];
            float4 wk = *(const float4*)&Wl[1][row];
            float4 wv = *(const float4*)&Wl[2][row];
            aq[j][0] = fmaf(wq.x,xv0.x, fmaf(wq.y,xv1.x, fmaf(wq.z,xv2.x, fmaf(wq.w,xv3.x, aq[j][0]))));
            aq[j][1] = fmaf(wq.x,xv0.y, fmaf(wq.y,xv1.y, fmaf(wq.z,xv2.y, fmaf(wq.w,xv3.y, aq[j][1]))));
            ak[j][0] = fmaf(wk.x,xv0.x, fmaf(wk.y,xv1.x, fmaf(wk.z,xv2.x, fmaf(wk.w,xv3.x, ak[j][0]))));
            ak[j][1] = fmaf(wk.x,xv0.y, fmaf(wk.y,xv1.y, fmaf(wk.z,xv2.y, fmaf(wk.w,xv3.y, ak[j][1]))));
            av[j][0] = fmaf(wv.x,xv0.x, fmaf(wv.y,xv1.x, fmaf(wv.z,xv2.x, fmaf(wv.w,xv3.x, av[j][0]))));
            av[j][1] = fmaf(wv.x,xv0.y, fmaf(wv.y,xv1.y, fmaf(wv.z,xv2.y, fmaf(wv.w,xv3.y, av[j][1]))));
        }
    }

    const int px = px0 + lane*2;
    const size_t base = ((size_t)n*HW + px)*CC + oc0;
    half4 vq0, vq1, vk0, vk1;
    #pragma unroll
    for (int j = 0; j < 4; ++j) {
        vq0[j] = (f16)aq[j][0]; vq1[j] = (f16)aq[j][1];
        vk0[j] = (f16)ak[j][0]; vk1[j] = (f16)ak[j][1];
    }
    *(half4*)&q[base]      = vq0;  *(half4*)&q[base + CC] = vq1;
    *(half4*)&k[base]      = vk0;  *(half4*)&k[base + CC] = vk1;

    #pragma unroll
    for (int j = 0; j < 4; ++j) {
        size_t gi = ((size_t)n*CC + oc0 + j)*HW + px;
        f16 g0 = (f16)((h0[gi]   + h1[gi]  ) * av[j][0]);
        f16 g1 = (f16)((h0[gi+1] + h1[gi+1]) * av[j][1]);
        gv[gi]   = g0;
        gv[gi+1] = g1;
    }

    float* slot = ws + PART_OFF + (size_t)(n*(HW/128) + blockIdx.x)*256;
    #pragma unroll
    for (int j = 0; j < 4; ++j) {
        float v0 = aq[j][0] + aq[j][1];
        float v1 = aq[j][0]*aq[j][0] + aq[j][1]*aq[j][1];
        float v2 = ak[j][0] + ak[j][1];
        float v3 = ak[j][0]*ak[j][0] + ak[j][1]*ak[j][1];
        #pragma unroll
        for (int off = 32; off > 0; off >>= 1) {
            v0 += __shfl_down(v0, off);
            v1 += __shfl_down(v1, off);
            v2 += __shfl_down(v2, off);
            v3 += __shfl_down(v3, off);
        }
        if (lane == 0) {
            slot[      oc0 + j] = v0;
            slot[ 64 + oc0 + j] = v1;
            slot[128 + oc0 + j] = v2;
            slot[192 + oc0 + j] = v3;
        }
    }
}

// ---------------------------------------------------------------------------
// apply: folds BN stats redundantly per block, then y = relu(s*y+t) in place,
// 16 f16/thread. blockIdx.y: 0=q, 1=k (k pre-scaled by log2e). (r12, kept)
// ---------------------------------------------------------------------------
__global__ __launch_bounds__(256)
void apply_kernel(f16* __restrict__ q, f16* __restrict__ k,
                  const float* __restrict__ ws,
                  const float* __restrict__ gq, const float* __restrict__ betaq,
                  const float* __restrict__ gk, const float* __restrict__ betak)
{
    __shared__ float tot[128];
    __shared__ float sc[CC], sh[CC];
    const int t = threadIdx.x;
    const int tens = blockIdx.y;

    if (t < 128) {
        const float* base = ws + PART_OFF + tens*128 + t;
        float acc = 0.0f;
        #pragma unroll 8
        for (int s = 0; s < NSLOT; ++s) acc += base[(size_t)s*256];
        tot[t] = acc;
    }
    __syncthreads();
    if (t < 64) {
        float mean = tot[t] * (1.0f / NT);
        float var  = tot[64 + t] * (1.0f / NT) - mean*mean;
        if (tens == 0) {
            float s = gq[t] * rsqrtf(var + EPSV);
            sc[t] = s;  sh[t] = betaq[t] - mean*s;
        } else {
            float s = gk[t] * rsqrtf(var + EPSV);
            sc[t] = s * LOG2E;  sh[t] = (betak[t] - mean*s) * LOG2E;
        }
    }
    __syncthreads();

    f16* p = tens ? k : q;
    const size_t e0 = ((size_t)blockIdx.x * 256 + t) * 16;
    const int c0 = (int)(e0 & 63);

    half8 v0 = *(half8*)&p[e0], v1 = *(half8*)&p[e0 + 8];
    half8 o0, o1;
    #pragma unroll
    for (int j = 0; j < 8; ++j) {
        o0[j] = (f16)fmaxf(fmaf(sc[c0+j],   (float)v0[j], sh[c0+j]),   0.0f);
        o1[j] = (f16)fmaxf(fmaf(sc[c0+8+j], (float)v1[j], sh[c0+8+j]), 0.0f);
    }
    *(half8*)&p[e0]     = o0;
    *(half8*)&p[e0 + 8] = o1;
}

// ---------------------------------------------------------------------------
// MFMA flash attention — r18: LDS-staged K/GV shared across waves.
// r13-r17 wall: occupancy x per-wave reg state = const. Register-resident
// operands force either 2 waves/SIMD (r13, 66 us) or spill/no-pipeline
// (r14-r17, 98-144 us). r18 moves the K/GV tiles to LDS, shared by wave
// pairs -> per-wave state ~85 regs -> 16 waves/CU AND a real pipeline.
//
// Decomposition: block = 8 waves = (qi in 0..1 q-tiles of 16 rows) x
// (si in 0..3 key-splits of 1024 keys). Waves (0,si),(1,si) share si's
// tiles. grid (HW/32, NB) = 512 blocks x 512 thr = 2 blocks/CU.
// Per step (32 keys): reg-stage loads issued at top (T14: global latency
// hidden under compute), compute on buf[cur], ds_write staged -> buf[cur^1],
// one barrier. 32 steps. In-block merge over si (r13's proven Obuf pattern).
// Defer-max THR=8 + scalar accL (r17, numerically validated).
//
// LDS 64 KB: Ks[si][buf] 4 KB each (32 KB) + GVs[si][buf] (32 KB); after the
// loop Obuf(32 KB)/MLbuf(1 KB) alias the dead staging region.
// K tile [32 rows][64 ch] is the 128B-row bank-conflict shape -> XOR swizzle
// elem ^= (row&7)<<3 on BOTH ds_write and ds_read (involution; verified
// content[A]=K[A]). GV tile [64 ch][32 keys]: elem ^= (ch&3)<<3.
// SUCCESS CRITERIA: WRITE_SIZE ~4 MB, VGPR ~90-110, bank-conflicts ~0,
// Occupancy ~45-50%, attn < 35 us.
// Layout (validated r4-r11): mfma(X,Y) -> D[p=quad*4+reg <- X row][q=lane&15 <- Y row].
// ---------------------------------------------------------------------------
__global__ __launch_bounds__(512, 4)
void attn_kernel(const f16* __restrict__ q, const f16* __restrict__ k,
                 const f16* __restrict__ gv, float* __restrict__ out)
{
    __shared__ alignas(16) char SM[65536];
    f16 (* const Ks)[2][2048]    = reinterpret_cast<f16(*)[2][2048]>(SM);          // [si][buf][32*64]
    f16 (* const GVs)[2][2048]   = reinterpret_cast<f16(*)[2][2048]>(SM + 32768);  // [si][buf][64*32]
    float (* const Obuf)[4][256] = reinterpret_cast<float(*)[4][256]>(SM);         // aliases Ks after loop
    float (* const MLbuf)[8][16] = reinterpret_cast<float(*)[8][16]>(SM + 32768);  // aliases GVs[0][0] head

    const int t    = threadIdx.x;
    const int n    = blockIdx.y;
    const int w    = t >> 6;
    const int lane = t & 63;
    const int m16  = lane & 15;
    const int kb   = lane >> 4;
    const int qi   = w >> 2;                 // q-tile owner (0..1)
    const int si   = w & 3;                  // key-split (0..3)
    const int q0g  = blockIdx.x * 32 + qi * 16;

    // Q fragments: rows q0g+m16, channels kb*8 (+32)
    half8 qf0, qf1;
    {
        const size_t qb = ((size_t)n*HW + q0g + m16)*CC + kb*8;
        qf0 = *(const half8*)&q[qb];
        qf1 = *(const half8*)&q[qb + 32];
    }

    const f16* kn  = k  + (size_t)n*HW*CC;
    const f16* gvn = gv + (size_t)n*CC*HW;

    // staging lane constants.  K stager (qi==0): 4 KB tile, lane covers
    // row rl (+o*8), col-chunk cl (8 f16).  GV stager (qi==1): ch chl
    // (+o*16), key-chunk kcl (8 f16).
    const int rl  = lane >> 3, cl  = lane & 7;
    const int chl = lane >> 2, kcl = lane & 3;
    const int    srcK = rl*CC + cl*8;
    const int    dstK = rl*CC + ((cl ^ rl) * 8);               // row&7 == rl for all o
    const size_t srcG = (size_t)chl*HW + kcl*8;
    const int    dstG = chl*32 + ((kcl ^ (chl & 3)) * 8);      // ch&3 == chl&3 for all o

    const int kt00 = si * 1024;

    // read-side swizzled element offsets
    const int swzk = (m16 & 7) << 3;
    const int swzg = (m16 & 3) << 3;
    const int e0k  = (kb*8)      ^ swzk;
    const int e1k  = (kb*8 + 32) ^ swzk;

    half8 stg[4];

#define STAGE_LOAD(IT) do {                                                   \
    const int kt_ = kt00 + (IT)*32;                                           \
    if (qi == 0) {                                                            \
        const f16* s_ = kn + (size_t)kt_*CC + srcK;                           \
        stg[0] = *(const half8*)(s_);                                         \
        stg[1] = *(const half8*)(s_ +  8*CC);                                 \
        stg[2] = *(const half8*)(s_ + 16*CC);                                 \
        stg[3] = *(const half8*)(s_ + 24*CC);                                 \
    } else {                                                                  \
        const f16* s_ = gvn + srcG + kt_;                                     \
        stg[0] = *(const half8*)(s_);                                         \
        stg[1] = *(const half8*)(s_ + (size_t)16*HW);                         \
        stg[2] = *(const half8*)(s_ + (size_t)32*HW);                         \
        stg[3] = *(const half8*)(s_ + (size_t)48*HW);                         \
    }                                                                         \
} while (0)

#define STAGE_WRITE(BUF) do {                                                 \
    if (qi == 0) {                                                            \
        f16* d_ = &Ks[si][BUF][dstK];                                         \
        *(half8*)(d_)        = stg[0];                                        \
        *(half8*)(d_ +  512) = stg[1];                                        \
        *(half8*)(d_ + 1024) = stg[2];                                        \
        *(half8*)(d_ + 1536) = stg[3];                                        \
    } else {                                                                  \
        f16* d_ = &GVs[si][BUF][dstG];                                        \
        *(half8*)(d_)        = stg[0];                                        \
        *(half8*)(d_ +  512) = stg[1];                                        \
        *(half8*)(d_ + 1024) = stg[2];                                        \
        *(half8*)(d_ + 1536) = stg[3];                                        \
    }                                                                         \
} while (0)

    float4v accO[4];
    #pragma unroll
    for (int ct = 0; ct < 4; ++ct) accO[ct] = (float4v){0.f,0.f,0.f,0.f};
    float accL = 0.0f;
    float mreg = -INFINITY;

#define COMPUTE(CUR) do {                                                     \
    const f16* Kb_ = &Ks[si][CUR][0];                                         \
    const f16* Gb_ = &GVs[si][CUR][0];                                        \
    half8 kh00_ = *(const half8*)&Kb_[ m16*CC       + e0k];                   \
    half8 kh01_ = *(const half8*)&Kb_[ m16*CC       + e1k];                   \
    half8 kh10_ = *(const half8*)&Kb_[(m16+16)*CC   + e0k];                   \
    half8 kh11_ = *(const half8*)&Kb_[(m16+16)*CC   + e1k];                   \
    float4v s0_ = {0.f,0.f,0.f,0.f}, s1_ = {0.f,0.f,0.f,0.f};                 \
    s0_ = __builtin_amdgcn_mfma_f32_16x16x32_f16(kh00_, qf0, s0_, 0,0,0);     \
    s0_ = __builtin_amdgcn_mfma_f32_16x16x32_f16(kh01_, qf1, s0_, 0,0,0);     \
    s1_ = __builtin_amdgcn_mfma_f32_16x16x32_f16(kh10_, qf0, s1_, 0,0,0);     \
    s1_ = __builtin_amdgcn_mfma_f32_16x16x32_f16(kh11_, qf1, s1_, 0,0,0);     \
    float v_ = fmaxf(fmaxf(fmaxf(s0_[0],s0_[1]), fmaxf(s0_[2],s0_[3])),       \
                     fmaxf(fmaxf(s1_[0],s1_[1]), fmaxf(s1_[2],s1_[3])));      \
    v_ = fmaxf(v_, __shfl_xor(v_, 16));                                       \
    v_ = fmaxf(v_, __shfl_xor(v_, 32));                                       \
    if (__any(v_ > mreg + THRV)) {                                            \
        float mn_ = fmaxf(mreg, v_);                                          \
        float al_ = exp2f(mreg - mn_);                                        \
        mreg = mn_;  accL *= al_;                                             \
        _Pragma("unroll") for (int ct_ = 0; ct_ < 4; ++ct_) {                 \
            accO[ct_][0]*=al_; accO[ct_][1]*=al_;                             \
            accO[ct_][2]*=al_; accO[ct_][3]*=al_;                             \
        }                                                                     \
    }                                                                         \
    float p0_=exp2f(s0_[0]-mreg), p1_=exp2f(s0_[1]-mreg);                     \
    float p2_=exp2f(s0_[2]-mreg), p3_=exp2f(s0_[3]-mreg);                     \
    float p4_=exp2f(s1_[0]-mreg), p5_=exp2f(s1_[1]-mreg);                     \
    float p6_=exp2f(s1_[2]-mreg), p7_=exp2f(s1_[3]-mreg);                     \
    accL += ((p0_+p1_)+(p2_+p3_)) + ((p4_+p5_)+(p6_+p7_));                    \
    half4 pfa_, pfb_;                                                         \
    pfa_[0]=(f16)p0_; pfa_[1]=(f16)p1_; pfa_[2]=(f16)p2_; pfa_[3]=(f16)p3_;   \
    pfb_[0]=(f16)p4_; pfb_[1]=(f16)p5_; pfb_[2]=(f16)p6_; pfb_[3]=(f16)p7_;   \
    _Pragma("unroll") for (int ct_ = 0; ct_ < 4; ++ct_) {                     \
        const int gb_ = (ct_*16 + m16)*32;                                    \
        half4 g0_ = *(const half4*)&Gb_[gb_ + ((kb*4)      ^ swzg)];          \
        half4 g1_ = *(const half4*)&Gb_[gb_ + ((kb*4 + 16) ^ swzg)];          \
        float4v o_ = accO[ct_];                                               \
        o_ = __builtin_amdgcn_mfma_f32_16x16x16f16(g0_, pfa_, o_, 0,0,0);     \
        accO[ct_] = __builtin_amdgcn_mfma_f32_16x16x16f16(g1_, pfb_, o_, 0,0,0); \
    }                                                                         \
} while (0)

    // prologue: tile 0 -> buf 0
    STAGE_LOAD(0);
    STAGE_WRITE(0);
    __syncthreads();

    for (int it = 0; it < 31; ++it) {
        const int cur = it & 1;
        STAGE_LOAD(it + 1);          // global latency hides under COMPUTE
        COMPUTE(cur);
        STAGE_WRITE(cur ^ 1);
        __syncthreads();
    }
    COMPUTE(1);                      // tile 31 sits in buf 1

    // cross-quad l, publish (m, l) per q-row
    float lq = accL;
    lq += __shfl_xor(lq, 16);
    lq += __shfl_xor(lq, 32);
    if (kb == 0) {
        MLbuf[0][w][m16] = mreg;
        MLbuf[1][w][m16] = lq;
    }
    __syncthreads();

    // shared max frame for own q-tile; scale own partials
    const int wb = qi * 4;
    {
        float M_ = fmaxf(fmaxf(MLbuf[0][wb][m16],   MLbuf[0][wb+1][m16]),
                         fmaxf(MLbuf[0][wb+2][m16], MLbuf[0][wb+3][m16]));
        float f_ = exp2f(mreg - M_);
        #pragma unroll
        for (int ct = 0; ct < 4; ++ct) {
            accO[ct][0]*=f_; accO[ct][1]*=f_; accO[ct][2]*=f_; accO[ct][3]*=f_;
        }
    }
    #pragma unroll
    for (int ct = 0; ct < 4; ++ct)
        ((float4*)&Obuf[w][ct][0])[lane] =
            (float4){accO[ct][0], accO[ct][1], accO[ct][2], accO[ct][3]};
    __syncthreads();

    // sum over si and write: wave w handles (q-tile w>>2, ct w&3)
    {
        const int qi2 = w >> 2, ct2 = w & 3, wb2 = qi2 * 4;
        float4 s  = ((float4*)&Obuf[wb2  ][ct2][0])[lane];
        float4 a1 = ((float4*)&Obuf[wb2+1][ct2][0])[lane];
        float4 a2 = ((float4*)&Obuf[wb2+2][ct2][0])[lane];
        float4 a3 = ((float4*)&Obuf[wb2+3][ct2][0])[lane];
        s.x += a1.x + a2.x + a3.x;
        s.y += a1.y + a2.y + a3.y;
        s.z += a1.z + a2.z + a3.z;
        s.w += a1.w + a2.w + a3.w;
        float m0 = MLbuf[0][wb2  ][m16], m1 = MLbuf[0][wb2+1][m16];
        float m2 = MLbuf[0][wb2+2][m16], m3 = MLbuf[0][wb2+3][m16];
        float M_ = fmaxf(fmaxf(m0, m1), fmaxf(m2, m3));
        float L_ = MLbuf[1][wb2  ][m16] * exp2f(m0 - M_)
                 + MLbuf[1][wb2+1][m16] * exp2f(m1 - M_)
                 + MLbuf[1][wb2+2][m16] * exp2f(m2 - M_)
                 + MLbuf[1][wb2+3][m16] * exp2f(m3 - M_);
        const float iv = 1.0f / L_;
        const int chb = ct2*16 + kb*4;
        const int row = blockIdx.x*32 + qi2*16 + m16;
        out[((size_t)n*CC + chb + 0)*HW + row] = s.x * iv;
        out[((size_t)n*CC + chb + 1)*HW + row] = s.y * iv;
        out[((size_t)n*CC + chb + 2)*HW + row] = s.z * iv;
        out[((size_t)n*CC + chb + 3)*HW + row] = s.w * iv;
    }
#undef COMPUTE
#undef STAGE_WRITE
#undef STAGE_LOAD
}

// ---------------------------------------------------------------------------
extern "C" void kernel_launch(void* const* d_in, const int* in_sizes, int n_in,
                              void* d_out, int out_size, void* d_ws, size_t ws_size,
                              hipStream_t stream)
{
    const float* low   = (const float*)d_in[0];
    const float* h0    = (const float*)d_in[1];
    const float* h1    = (const float*)d_in[2];
    const float* Wq    = (const float*)d_in[3];
    const float* bq    = (const float*)d_in[4];
    const float* gq    = (const float*)d_in[5];
    const float* betaq = (const float*)d_in[6];
    const float* Wk    = (const float*)d_in[7];
    const float* bk    = (const float*)d_in[8];
    const float* gk    = (const float*)d_in[9];
    const float* betak = (const float*)d_in[10];
    const float* Wv    = (const float*)d_in[11];
    const float* bv    = (const float*)d_in[12];

    float* wsf = (float*)d_ws;
    float* out = (float*)d_out;

    f16* q  = (f16*)((char*)d_ws + TEN_OFF);
    f16* k  = q + NELEM;
    f16* gv = k + NELEM;

    conv2_kernel<<<dim3(HW/128, NB, 4), 256, 0, stream>>>(
        low, h0, h1, Wq, bq, Wk, bk, Wv, bv, wsf, q, k, gv);

    apply_kernel<<<dim3((int)(NELEM/(256*16)), 2), 256, 0, stream>>>(
        q, k, wsf, gq, betaq, gk, betak);

    attn_kernel<<<dim3(HW/32, NB), 512, 0, stream>>>(q, k, gv, out);
}